// Round 8
// baseline (8000.752 us; speedup 1.0000x reference)
//
#include <hip/hip_runtime.h>
#include <stdint.h>

// ---------------------------------------------------------------------------
// LSTM decoder: B=256, S=1024, H=256, 4H=1024 gates (i,f,g,o).
// Round-8: N-SPLIT RECURRENCE. 64 LSTM blocks = 16 batch-groups x 4 hidden
// slices. Each CU owns 256 gate rows (4 gates x 64 j) = 128KB W_hh held
// ENTIRELY IN REGISTERS (16 frags/wave = 64 VGPR; total live ~110 < the
// 128-reg cap this toolchain enforces). Per step, CUs exchange their 64-j
// h-slices via global memory with device-scope release/acquire flags
// (__hip_atomic_*, AGENT scope). hx is parity double-buffered (slot (s+1)&1
// written, slot s&1 read) so flag causality forbids overwrite races.
// Flags zeroed by pack_misc each launch -> graph-replay safe; targets are
// monotonic c*128+s across the 8 fused dispatches.
// ---------------------------------------------------------------------------

using bf16x8 = __attribute__((ext_vector_type(8))) __bf16;
using f32x4  = __attribute__((ext_vector_type(4))) float;
using u32x4  = __attribute__((ext_vector_type(4))) uint32_t;
using u32x2  = __attribute__((ext_vector_type(2))) uint32_t;
using u16x2  = __attribute__((ext_vector_type(2))) uint16_t;

#define NCHUNK 8

// workspace layout (bytes)
#define XS_OFF   0ull
#define XS_SZ    134217728ull
#define WIH_OFF  (XS_OFF + XS_SZ)
#define W_SZ     524288ull
#define WHH_OFF  (WIH_OFF + W_SZ)
#define XP0_OFF  (WHH_OFF + W_SZ)
#define XP_SZ    67108864ull          // 64 slices * 128 s * 16 nt * 64 lane * 8B
#define XP1_OFF  (XP0_OFF + XP_SZ)
#define HX_OFF   (XP1_OFF + XP_SZ)    // 2 slots * 64 slices * 2KB = 256KB
#define HX_SZ    262144ull
#define FLG_OFF  (HX_OFF + HX_SZ)     // 64 flags, 64B apart
#define FLG_SZ   4096ull
#define CST_OFF  (FLG_OFF + FLG_SZ)   // 64 * 1024 fp32
#define CST_SZ   262144ull
#define BIAS_OFF (CST_OFF + CST_SZ)

// LSTM LDS: hbuf 8KB | gbuf 16KB | staging 2KB  (request 96KB -> 1 block/CU)
#define HBUF_OFF 0
#define GBUF_OFF 8192
#define STG_OFF  24576
#define LDS_BYTES 98304

#define SC_IFO -1.442695041f     // -log2(e)
#define SC_G   -2.885390082f     // -2*log2(e)

__device__ __forceinline__ uint16_t f2bf(float f) {
  uint32_t x = __float_as_uint(f);
  x += 0x7fffu + ((x >> 16) & 1u);
  return (uint16_t)(x >> 16);
}
__device__ __forceinline__ float bf2f(uint16_t u) {
  return __uint_as_float(((uint32_t)u) << 16);
}
__device__ __forceinline__ float frcp(float x) { return __builtin_amdgcn_rcpf(x); }
__device__ __forceinline__ float exp2a(float x) {
  float r; asm("v_exp_f32 %0, %1" : "=v"(r) : "v"(x)); return r;
}
__device__ __forceinline__ f32x4 mfma16(u32x4 a, u32x4 b, f32x4 c) {
  return __builtin_amdgcn_mfma_f32_16x16x32_bf16(
      __builtin_bit_cast(bf16x8, a), __builtin_bit_cast(bf16x8, b), c, 0, 0, 0);
}
__device__ __forceinline__ uint32_t flag_ld(const uint32_t* p) {
  return __hip_atomic_load(p, __ATOMIC_ACQUIRE, __HIP_MEMORY_SCOPE_AGENT);
}
__device__ __forceinline__ void flag_st(uint32_t* p, uint32_t v) {
  __hip_atomic_store(p, v, __ATOMIC_RELEASE, __HIP_MEMORY_SCOPE_AGENT);
}

// ---------------------------------------------------------------------------
// P1: pack shifted input sequence (S-MAJOR rows: r = s*256 + b) into
// A-fragment layout xsp[m16][kt][lane][8bf16].  (unchanged, verified)
// ---------------------------------------------------------------------------
__global__ __launch_bounds__(256) void pack_x_k(const float* __restrict__ x,
                                                const float* __restrict__ hn,
                                                uint16_t* __restrict__ xsp) {
  __shared__ uint16_t tile[64 * 256];
  const int t = blockIdx.x;
  const int tid = threadIdx.x;
  for (int pass = 0; pass < 2; ++pass) {
    const int r = tid >> 2;
    const int qq = tid & 3;
    const int rg = t * 128 + pass * 64 + r;
    const int s = rg >> 8, b = rg & 255;
    const float* src = s ? (x + ((size_t)b * 1024 + (s - 1)) * 256)
                         : (hn + (size_t)b * 256);
#pragma unroll
    for (int i = 0; i < 64; i += 2) {
      float2 v = *(const float2*)(src + qq * 64 + i);
      uint32_t kb = (uint32_t)(qq * 64 + i) * 2u;
      uint32_t addr = (uint32_t)r * 512u + (kb ^ (((uint32_t)r & 7u) << 4));
      u16x2 pr; pr.x = f2bf(v.x); pr.y = f2bf(v.y);
      *(u16x2*)((char*)tile + addr) = pr;
    }
    __syncthreads();
#pragma unroll
    for (int ff = 0; ff < 8; ++ff) {
      int task = ff * 256 + tid;
      int frag = task >> 6, lam = task & 63;
      int mt = frag >> 3, kt = frag & 7;
      int row = mt * 16 + (lam & 15);
      uint32_t kb = (uint32_t)(kt * 64 + (lam >> 4) * 16);
      u32x4 d = *(const u32x4*)((const char*)tile + row * 512 +
                                (kb ^ (((uint32_t)row & 7u) << 4)));
      size_t m16 = (size_t)t * 8 + pass * 4 + mt;
      *(u32x4*)(xsp + ((m16 * 8 + kt) * 64 + lam) * 8) = d;
    }
    __syncthreads();
  }
}

// ---------------------------------------------------------------------------
// P2: W packs (pre-scaled), bias, flags=0, hx slot-0 = h0 (A-frag slices),
// c0 per-cell state.
// ---------------------------------------------------------------------------
__global__ __launch_bounds__(256) void pack_misc_k(
    const float* __restrict__ wih, const float* __restrict__ whh,
    const float* __restrict__ bih, const float* __restrict__ bhh,
    const float* __restrict__ hn, const float* __restrict__ cn,
    uint16_t* __restrict__ wihp, uint16_t* __restrict__ whhp,
    float* __restrict__ bias, char* __restrict__ hx,
    uint32_t* __restrict__ flags, float* __restrict__ cst) {
  const int blk = blockIdx.x, tid = threadIdx.x;
  if (blk < 32) {
    __shared__ uint16_t tile[64 * 256];
    const float* W = (blk < 16) ? wih : whh;
    uint16_t* WP = (blk < 16) ? wihp : whhp;
    const int rowbase = (blk & 15) * 64;
    const int r = tid >> 2, qq = tid & 3;
    const int n = rowbase + r;
    const float sc = ((n >> 8) == 2) ? SC_G : SC_IFO;
    const float* src = W + (size_t)n * 256;
#pragma unroll
    for (int i = 0; i < 64; i += 2) {
      float2 v = *(const float2*)(src + qq * 64 + i);
      uint32_t kb = (uint32_t)(qq * 64 + i) * 2u;
      uint32_t addr = (uint32_t)r * 512u + (kb ^ (((uint32_t)r & 7u) << 4));
      u16x2 pr; pr.x = f2bf(v.x * sc); pr.y = f2bf(v.y * sc);
      *(u16x2*)((char*)tile + addr) = pr;
    }
    __syncthreads();
#pragma unroll
    for (int ff = 0; ff < 8; ++ff) {
      int task = ff * 256 + tid;
      int frag = task >> 6, lam = task & 63;
      int mt = frag >> 3, kt = frag & 7;
      int row = mt * 16 + (lam & 15);
      uint32_t kb = (uint32_t)(kt * 64 + (lam >> 4) * 16);
      u32x4 d = *(const u32x4*)((const char*)tile + row * 512 +
                                (kb ^ (((uint32_t)row & 7u) << 4)));
      size_t nt = (size_t)(blk & 15) * 4 + mt;
      *(u32x4*)(WP + ((nt * 8 + kt) * 64 + lam) * 8) = d;
    }
  } else if (blk == 32) {
    for (int i = tid; i < 4096; i += 256) {
      float sc = ((i >> 8) == 2) ? SC_G : SC_IFO;
      bias[i] = (bih[i] + bhh[i]) * sc;
    }
    for (int i = tid; i < 1024; i += 256) flags[i] = 0u;
  } else if (blk == 33) {
    // hx slot 0 init: hx[slice][kt_loc][lane][8 u16]
    for (int it = 0; it < 32; ++it) {
      int item = it * 256 + tid;          // 8192 items
      int lane = item & 63;
      int ktl = (item >> 6) & 1;
      int slice = item >> 7;
      int g = slice >> 2, ns = slice & 3;
      int b = g * 16 + (lane & 15);
      int k0 = ns * 64 + ktl * 32 + (lane >> 4) * 8;
      union { uint16_t s[8]; u32x4 v; } u;
#pragma unroll
      for (int e = 0; e < 8; ++e) u.s[e] = f2bf(hn[(size_t)b * 256 + k0 + e]);
      *(u32x4*)(hx + (size_t)slice * 2048 + ktl * 1024 + lane * 16) = u.v;
    }
  } else {
    // blk 34,35: c0 per cell: cst[slice*1024 + c], c = m*64 + jl
    for (int it = 0; it < 128; ++it) {
      int idx = (blk - 34) * 32768 + it * 256 + tid;
      int slice = idx >> 10, ci = idx & 1023;
      int g = slice >> 2, ns = slice & 3;
      int b = g * 16 + (ci >> 6);
      int j = ns * 64 + (ci & 63);
      cst[idx] = cn[(size_t)b * 256 + j];
    }
  }
}

// ---------------------------------------------------------------------------
// fused: blocks 0-63 LSTM (slice = g*4+ns) chunk `lstm_chunk`;
//        blocks 64..575 x_proj GEMM chunk `gemm_chunk`.
// ---------------------------------------------------------------------------
__global__ __launch_bounds__(512) void fused_k(
    const uint16_t* __restrict__ xsp, const uint16_t* __restrict__ wihp,
    const uint16_t* __restrict__ whhp, const float* __restrict__ bias,
    uint16_t* __restrict__ xp0, uint16_t* __restrict__ xp1,
    char* __restrict__ hx, uint32_t* __restrict__ flags,
    float* __restrict__ cst, float* __restrict__ out,
    int lstm_chunk, int gemm_chunk) {
  extern __shared__ __align__(16) char lds[];
  const int tid = threadIdx.x;
  const int l = tid & 63;
  const int w = tid >> 6;

  if (blockIdx.x < 64) {
    // ======================= LSTM path =======================
    if (lstm_chunk < 0) return;
    const int c = lstm_chunk;
    const uint32_t cb = (uint32_t)(c * 128);
    const int slice = blockIdx.x;
    const int g = slice >> 2, ns = slice & 3;
    const uint16_t* __restrict__ xp = (c & 1) ? xp1 : xp0;
    char* hbuf = lds + HBUF_OFF;
    float* gbuf = (float*)(lds + GBUF_OFF);
    char* stg = lds + STG_OFF;

    // ---- W: wave w owns nt_local {2w, 2w+1}; 16 frags in REGISTERS ----
    u32x4 wr0[8], wr1[8];
    {
      int nl0 = 2 * w, nl1 = 2 * w + 1;
      int ng0 = (nl0 >> 2) * 16 + ns * 4 + (nl0 & 3);
      int ng1 = (nl1 >> 2) * 16 + ns * 4 + (nl1 & 3);
#pragma unroll
      for (int kt = 0; kt < 8; ++kt) {
        wr0[kt] = *(const u32x4*)(whhp + (((size_t)ng0 * 8 + kt) * 64 + l) * 8);
        wr1[kt] = *(const u32x4*)(whhp + (((size_t)ng1 * 8 + kt) * 64 + l) * 8);
      }
    }
    // c state: 2 cells per thread (c_idx = tid, tid+512; c = m*64+jl)
    float cc0 = cst[(size_t)slice * 1024 + tid];
    float cc1 = cst[(size_t)slice * 1024 + tid + 512];

    // cell-phase constants per thread
    int m0 = tid >> 6, jl0 = tid & 63;
    int m1 = (tid + 512) >> 6, jl1 = jl0;
    float* gp0 = gbuf + (jl0 >> 4) * 256 + m0 * 16 + (jl0 & 15);
    float* gp1 = gbuf + (jl1 >> 4) * 256 + m1 * 16 + (jl1 & 15);
    char* sp0 = stg + (jl0 >> 5) * 1024 + (((jl0 & 31) >> 3) * 16 + m0) * 16 + (jl0 & 7) * 2;
    char* sp1 = stg + (jl1 >> 5) * 1024 + (((jl1 & 31) >> 3) * 16 + m1) * 16 + (jl1 & 7) * 2;
    float* op0 = out + ((size_t)(g * 16 + m0) * 1024 + (size_t)c * 128) * 256 + ns * 64 + jl0;
    float* op1 = out + ((size_t)(g * 16 + m1) * 1024 + (size_t)c * 128) * 256 + ns * 64 + jl1;
    // A-phase bases
    const char* xpb = (const char*)xp + (size_t)slice * 1048576 + (size_t)(2 * w) * 512 + (size_t)l * 8;
    float* gb0 = gbuf + (2 * w) * 256 + ((l >> 4) * 4) * 16 + (l & 15);
    float* gb1 = gb0 + 256;

    // pre-loop: wave 0 fills OWN slice of hbuf from hx slot 0
    if (w == 0) {
      const char* src = hx + (size_t)slice * 2048 + (size_t)l * 32;
      u32x4 d0 = *(const u32x4*)src;
      u32x4 d1 = *(const u32x4*)(src + 16);
      *(u32x4*)(hbuf + ns * 2048 + l * 32) = d0;
      *(u32x4*)(hbuf + ns * 2048 + l * 32 + 16) = d1;
    }

#pragma unroll 1
    for (int s = 0; s < 128; ++s) {
      // ---- consume remote slices (waves 1..3) ----
      if (w >= 1 && w < 4) {
        const int nsr = (ns + w) & 3;
        const uint32_t tgt = cb + (uint32_t)s;
        if (l == 0) {
          while (flag_ld(&flags[(g * 4 + nsr) * 16]) < tgt)
            __builtin_amdgcn_s_sleep(2);
        }
        const char* src = hx + (size_t)(s & 1) * 131072 +
                          (size_t)(g * 4 + nsr) * 2048 + (size_t)l * 32;
        u32x4 d0 = *(const u32x4*)src;
        u32x4 d1 = *(const u32x4*)(src + 16);
        *(u32x4*)(hbuf + nsr * 2048 + l * 32) = d0;
        *(u32x4*)(hbuf + nsr * 2048 + l * 32 + 16) = d1;
      }
      __syncthreads();

      // ---- phase A: MFMA + xp add + gate-buffer write ----
      {
        const char* xc = xpb + (size_t)s * 8192;
        union { uint16_t sv[4]; u32x2 v; } xv0, xv1;
        xv0.v = *(const u32x2*)(xc);
        xv1.v = *(const u32x2*)(xc + 512);
        f32x4 acc0 = {}, acc1 = {};
#pragma unroll
        for (int kt = 0; kt < 8; ++kt) {
          u32x4 a = *(const u32x4*)(hbuf + kt * 1024 + l * 16);
          acc0 = mfma16(a, wr0[kt], acc0);
          acc1 = mfma16(a, wr1[kt], acc1);
        }
#pragma unroll
        for (int q = 0; q < 4; ++q) {
          gb0[q * 16] = acc0[q] + bf2f(xv0.sv[q]);
          gb1[q * 16] = acc1[q] + bf2f(xv1.sv[q]);
        }
      }
      __syncthreads();

      // ---- cell phase: 2 cells per thread ----
      {
        float xi = gp0[0], xf = gp0[1024], xg = gp0[2048], xo = gp0[3072];
        float I = frcp(1.f + exp2a(xi));
        float F = frcp(1.f + exp2a(xf));
        float T = fmaf(2.f, frcp(1.f + exp2a(xg)), -1.f);
        float O = frcp(1.f + exp2a(xo));
        float cv = fmaf(F, cc0, I * T);
        cc0 = cv;
        float hv = O * fmaf(2.f, frcp(1.f + exp2a(SC_G * cv)), -1.f);
        op0[(size_t)s * 256] = hv;
        *(uint16_t*)sp0 = f2bf(hv);
      }
      {
        float xi = gp1[0], xf = gp1[1024], xg = gp1[2048], xo = gp1[3072];
        float I = frcp(1.f + exp2a(xi));
        float F = frcp(1.f + exp2a(xf));
        float T = fmaf(2.f, frcp(1.f + exp2a(xg)), -1.f);
        float O = frcp(1.f + exp2a(xo));
        float cv = fmaf(F, cc1, I * T);
        cc1 = cv;
        float hv = O * fmaf(2.f, frcp(1.f + exp2a(SC_G * cv)), -1.f);
        op1[(size_t)s * 256] = hv;
        *(uint16_t*)sp1 = f2bf(hv);
      }
      __syncthreads();

      // ---- publish own slice (wave 0): staging -> hx[(s+1)&1] + flag ----
      if (w == 0) {
        u32x4 s0 = *(const u32x4*)(stg + l * 32);
        u32x4 s1 = *(const u32x4*)(stg + l * 32 + 16);
        char* dst = hx + (size_t)((s + 1) & 1) * 131072 +
                    (size_t)slice * 2048 + (size_t)l * 32;
        *(u32x4*)dst = s0;
        *(u32x4*)(dst + 16) = s1;
        // own slice also goes straight into hbuf for the next step
        *(u32x4*)(hbuf + ns * 2048 + l * 32) = s0;
        *(u32x4*)(hbuf + ns * 2048 + l * 32 + 16) = s1;
        __threadfence();
        if (l == 0) flag_st(&flags[slice * 16], cb + (uint32_t)(s + 1));
      }
    }
    // write back c state
    cst[(size_t)slice * 1024 + tid] = cc0;
    cst[(size_t)slice * 1024 + tid + 512] = cc1;
    return;
  }

  // ======================= x_proj GEMM path =======================
  if (gemm_chunk < 0) return;
  const int cg = gemm_chunk;
  const int bid = blockIdx.x - 64;   // 0..511
  const int sg = bid >> 4;           // s-group (4 seq positions)
  const int bb = bid & 15;           // batch group g

  f32x4 acc[4][2][4] = {};           // [mt][jj][gi]
#pragma unroll
  for (int kt = 0; kt < 8; ++kt) {
    u32x4 av[4];
#pragma unroll
    for (int mt = 0; mt < 4; ++mt) {
      size_t m16 = (size_t)(cg * 128 + sg * 4 + mt) * 16 + bb;
      av[mt] = *(const u32x4*)(xsp + ((m16 * 8 + kt) * 64 + l) * 8);
    }
    u32x4 bv[2][4];
#pragma unroll
    for (int jj = 0; jj < 2; ++jj)
#pragma unroll
      for (int gi = 0; gi < 4; ++gi) {
        size_t nt = (size_t)(gi * 16 + w * 2 + jj);
        bv[jj][gi] = *(const u32x4*)(wihp + ((nt * 8 + kt) * 64 + l) * 8);
      }
#pragma unroll
    for (int mt = 0; mt < 4; ++mt)
#pragma unroll
      for (int jj = 0; jj < 2; ++jj)
#pragma unroll
        for (int gi = 0; gi < 4; ++gi)
          acc[mt][jj][gi] = mfma16(av[mt], bv[jj][gi], acc[mt][jj][gi]);
  }
  uint16_t* __restrict__ xpo = (cg & 1) ? xp1 : xp0;
  float badd[2][4];
#pragma unroll
  for (int jj = 0; jj < 2; ++jj)
#pragma unroll
    for (int gi = 0; gi < 4; ++gi)
      badd[jj][gi] = bias[(gi * 16 + w * 2 + jj) * 16 + (l & 15)];
#pragma unroll
  for (int mt = 0; mt < 4; ++mt)
#pragma unroll
    for (int jj = 0; jj < 2; ++jj) {
      int ntt = w * 2 + jj;
      int slicex = bb * 4 + (ntt >> 2);
      int jt = ntt & 3;
      int s_loc = sg * 4 + mt;
#pragma unroll
      for (int gi = 0; gi < 4; ++gi) {
        union { uint16_t sv[4]; u32x2 v; } pk;
#pragma unroll
        for (int q = 0; q < 4; ++q)
          pk.sv[q] = f2bf(acc[mt][jj][gi][q] + badd[jj][gi]);
        *(u32x2*)(xpo + ((((size_t)slicex * 128 + s_loc) * 16 + gi * 4 + jt) * 64 + l) * 4) = pk.v;
      }
    }
}

// ---------------------------------------------------------------------------
extern "C" void kernel_launch(void* const* d_in, const int* in_sizes, int n_in,
                              void* d_out, int out_size, void* d_ws, size_t ws_size,
                              hipStream_t stream) {
  const float* x   = (const float*)d_in[0];
  const float* hn  = (const float*)d_in[1];
  const float* cn  = (const float*)d_in[2];
  const float* wih = (const float*)d_in[3];
  const float* whh = (const float*)d_in[4];
  const float* bih = (const float*)d_in[5];
  const float* bhh = (const float*)d_in[6];
  float* out = (float*)d_out;
  char* ws = (char*)d_ws;

  uint16_t* xsp   = (uint16_t*)(ws + XS_OFF);
  uint16_t* wihp  = (uint16_t*)(ws + WIH_OFF);
  uint16_t* whhp  = (uint16_t*)(ws + WHH_OFF);
  uint16_t* xp0   = (uint16_t*)(ws + XP0_OFF);
  uint16_t* xp1   = (uint16_t*)(ws + XP1_OFF);
  char*     hx    = ws + HX_OFF;
  uint32_t* flags = (uint32_t*)(ws + FLG_OFF);
  float*    cst   = (float*)(ws + CST_OFF);
  float*    bias  = (float*)(ws + BIAS_OFF);

  hipFuncSetAttribute(reinterpret_cast<const void*>(fused_k),
                      hipFuncAttributeMaxDynamicSharedMemorySize, LDS_BYTES);

  hipLaunchKernelGGL(pack_x_k, dim3(2048), dim3(256), 0, stream, x, hn, xsp);
  hipLaunchKernelGGL(pack_misc_k, dim3(36), dim3(256), 0, stream,
                     wih, whh, bih, bhh, hn, cn, wihp, whhp, bias, hx, flags, cst);
  for (int c = 0; c <= NCHUNK; ++c) {
    int lc = c - 1;
    int gc = (c < NCHUNK) ? c : -1;
    hipLaunchKernelGGL(fused_k, dim3(576), dim3(512), LDS_BYTES, stream,
                       xsp, wihp, whhp, bias, xp0, xp1, hx, flags, cst, out, lc, gc);
  }
}

// Round 9
// 4085.145 us; speedup vs baseline: 1.9585x; 1.9585x over previous
//
#include <hip/hip_runtime.h>
#include <stdint.h>

// ---------------------------------------------------------------------------
// LSTM decoder: B=256, S=1024, H=256, 4H=1024 gates (i,f,g,o).
// Round-9: 4-WAVE / 512-REG design. 16 LSTM blocks (16 batch rows each),
// 256 threads = 4 waves at amdgpu_waves_per_eu(1,1) -> unified budget
// 512 regs/wave (hypothesis H: prior rounds' 128 cap = arch half of 256 at
// 2 waves/EU; r2's 284-reg live set could never fit).
// Wave w owns j in [w*64,(w+1)*64) x all 4 gates = 16 nt x 8 kt = 128 frags:
//   96 frags (kt2-7) in plain VGPRs (384 regs, builtin MFMA consumption),
//   32 frags (kt0-1) in LDS (128KB + 16KB h double-buffer = 144KB).
// ZERO streamed W per step. Step split into 2 jt-halves (acc 32 regs live).
// Cell update fully wave-local (lane owns 16 cells). All-builtin MFMAs.
// ---------------------------------------------------------------------------

using bf16x8 = __attribute__((ext_vector_type(8))) __bf16;
using f32x4  = __attribute__((ext_vector_type(4))) float;
using u32x4  = __attribute__((ext_vector_type(4))) uint32_t;
using u32x2  = __attribute__((ext_vector_type(2))) uint32_t;
using u16x2  = __attribute__((ext_vector_type(2))) uint16_t;

#define NCHUNK 8

// workspace layout (bytes)
#define XS_OFF   0ull
#define XS_SZ    134217728ull
#define WIH_OFF  (XS_OFF + XS_SZ)
#define W_SZ     524288ull
#define WHH_OFF  (WIH_OFF + W_SZ)
#define XP0_OFF  (WHH_OFF + W_SZ)
#define XP_SZ    67108864ull          // 16 blk * 128 s * 4 w * 2 half * 64 lane * 64B
#define XP1_OFF  (XP0_OFF + XP_SZ)
#define HST_OFF  (XP1_OFF + XP_SZ)    // 16 blk * 8KB
#define HST_SZ   131072ull
#define CST_OFF  (HST_OFF + HST_SZ)   // 16 blk * 4 w * 64 l * 16 fp32
#define CST_SZ   262144ull
#define BIAS_OFF (CST_OFF + CST_SZ)

// LSTM LDS: 4 waves * 32KB W (kt0,1) = 131072, then 2 * 8KB h double-buffer
#define WLDS_PER_WAVE 32768
#define HOFF   131072
#define LDS_BYTES 147456

#define SC_IFO -1.442695041f     // -log2(e)
#define SC_G   -2.885390082f     // -2*log2(e)

__device__ __forceinline__ uint16_t f2bf(float f) {
  uint32_t x = __float_as_uint(f);
  x += 0x7fffu + ((x >> 16) & 1u);
  return (uint16_t)(x >> 16);
}
__device__ __forceinline__ float bf2f(uint16_t u) {
  return __uint_as_float(((uint32_t)u) << 16);
}
__device__ __forceinline__ float frcp(float x) { return __builtin_amdgcn_rcpf(x); }
__device__ __forceinline__ float exp2a(float x) {
  float r; asm("v_exp_f32 %0, %1" : "=v"(r) : "v"(x)); return r;
}
__device__ __forceinline__ f32x4 mfma16(u32x4 a, u32x4 b, f32x4 c) {
  return __builtin_amdgcn_mfma_f32_16x16x32_bf16(
      __builtin_bit_cast(bf16x8, a), __builtin_bit_cast(bf16x8, b), c, 0, 0, 0);
}

// ---------------------------------------------------------------------------
// P1: pack shifted input sequence (S-MAJOR rows: r = s*256 + b) into
// A-fragment layout xsp[m16][kt][lane][8bf16].  (unchanged, verified)
// ---------------------------------------------------------------------------
__global__ __launch_bounds__(256) void pack_x_k(const float* __restrict__ x,
                                                const float* __restrict__ hn,
                                                uint16_t* __restrict__ xsp) {
  __shared__ uint16_t tile[64 * 256];
  const int t = blockIdx.x;
  const int tid = threadIdx.x;
  for (int pass = 0; pass < 2; ++pass) {
    const int r = tid >> 2;
    const int qq = tid & 3;
    const int rg = t * 128 + pass * 64 + r;
    const int s = rg >> 8, b = rg & 255;
    const float* src = s ? (x + ((size_t)b * 1024 + (s - 1)) * 256)
                         : (hn + (size_t)b * 256);
#pragma unroll
    for (int i = 0; i < 64; i += 2) {
      float2 v = *(const float2*)(src + qq * 64 + i);
      uint32_t kb = (uint32_t)(qq * 64 + i) * 2u;
      uint32_t addr = (uint32_t)r * 512u + (kb ^ (((uint32_t)r & 7u) << 4));
      u16x2 pr; pr.x = f2bf(v.x); pr.y = f2bf(v.y);
      *(u16x2*)((char*)tile + addr) = pr;
    }
    __syncthreads();
#pragma unroll
    for (int ff = 0; ff < 8; ++ff) {
      int task = ff * 256 + tid;
      int frag = task >> 6, lam = task & 63;
      int mt = frag >> 3, kt = frag & 7;
      int row = mt * 16 + (lam & 15);
      uint32_t kb = (uint32_t)(kt * 64 + (lam >> 4) * 16);
      u32x4 d = *(const u32x4*)((const char*)tile + row * 512 +
                                (kb ^ (((uint32_t)row & 7u) << 4)));
      size_t m16 = (size_t)t * 8 + pass * 4 + mt;
      *(u32x4*)(xsp + ((m16 * 8 + kt) * 64 + lam) * 8) = d;
    }
    __syncthreads();
  }
}

// ---------------------------------------------------------------------------
// P2: W packs (pre-scaled by -log2e / -2log2e), bias, h0 A-frag state,
// c0 per-lane state (new [blk][w][l][16] layout).
// ---------------------------------------------------------------------------
__global__ __launch_bounds__(256) void pack_misc_k(
    const float* __restrict__ wih, const float* __restrict__ whh,
    const float* __restrict__ bih, const float* __restrict__ bhh,
    const float* __restrict__ hn, const float* __restrict__ cn,
    uint16_t* __restrict__ wihp, uint16_t* __restrict__ whhp,
    float* __restrict__ bias, uint16_t* __restrict__ hst, float* __restrict__ cst) {
  const int blk = blockIdx.x, tid = threadIdx.x;
  if (blk < 32) {
    __shared__ uint16_t tile[64 * 256];
    const float* W = (blk < 16) ? wih : whh;
    uint16_t* WP = (blk < 16) ? wihp : whhp;
    const int rowbase = (blk & 15) * 64;
    const int r = tid >> 2, qq = tid & 3;
    const int n = rowbase + r;
    const float sc = ((n >> 8) == 2) ? SC_G : SC_IFO;
    const float* src = W + (size_t)n * 256;
#pragma unroll
    for (int i = 0; i < 64; i += 2) {
      float2 v = *(const float2*)(src + qq * 64 + i);
      uint32_t kb = (uint32_t)(qq * 64 + i) * 2u;
      uint32_t addr = (uint32_t)r * 512u + (kb ^ (((uint32_t)r & 7u) << 4));
      u16x2 pr; pr.x = f2bf(v.x * sc); pr.y = f2bf(v.y * sc);
      *(u16x2*)((char*)tile + addr) = pr;
    }
    __syncthreads();
#pragma unroll
    for (int ff = 0; ff < 8; ++ff) {
      int task = ff * 256 + tid;
      int frag = task >> 6, lam = task & 63;
      int mt = frag >> 3, kt = frag & 7;
      int row = mt * 16 + (lam & 15);
      uint32_t kb = (uint32_t)(kt * 64 + (lam >> 4) * 16);
      u32x4 d = *(const u32x4*)((const char*)tile + row * 512 +
                                (kb ^ (((uint32_t)row & 7u) << 4)));
      size_t nt = (size_t)(blk & 15) * 4 + mt;
      *(u32x4*)(WP + ((nt * 8 + kt) * 64 + lam) * 8) = d;
    }
  } else if (blk == 32) {
    for (int i = tid; i < 4096; i += 256) {
      float sc = ((i >> 8) == 2) ? SC_G : SC_IFO;
      bias[i] = (bih[i] + bhh[i]) * sc;
    }
  } else if (blk == 33) {
    // h_state[lblk][kt][lam][8] (A-frag layout)
    for (int it = 0; it < 32; ++it) {
      int task = it * 256 + tid;
      int lam = task & 63;
      int kt = (task >> 6) & 7;
      int lb = task >> 9;
      int b = lb * 16 + (lam & 15);
      int k0 = kt * 32 + (lam >> 4) * 8;
      union { uint16_t s[8]; u32x4 v; } u;
#pragma unroll
      for (int j = 0; j < 8; ++j) u.s[j] = f2bf(hn[(size_t)b * 256 + k0 + j]);
      *(u32x4*)(hst + (size_t)task * 8) = u.v;
    }
  } else {
    // blk 34,35: cst[blk4][w][l][16], v = half*8 + jt*4 + q
    for (int it = 0; it < 128; ++it) {
      int idx = (blk - 34) * 32768 + it * 256 + tid;
      int v = idx & 15;
      int lq = (idx >> 4) & 63;
      int ww = (idx >> 10) & 3;
      int lb = idx >> 12;
      int h = v >> 3, jt = (v >> 2) & 1, q = v & 3;
      int b = lb * 16 + (lq >> 4) * 4 + q;
      int j = (ww * 4 + h * 2 + jt) * 16 + (lq & 15);
      cst[idx] = cn[(size_t)b * 256 + j];
    }
  }
}

// ---------------------------------------------------------------------------
// fused: blocks 0-15 persistent LSTM chunk `lstm_chunk` (128 steps);
//        blocks 16..271 x_proj GEMM chunk `gemm_chunk`.
// ---------------------------------------------------------------------------
__global__
__attribute__((amdgpu_flat_work_group_size(256, 256)))
__attribute__((amdgpu_waves_per_eu(1, 1)))
void fused_k(
    const uint16_t* __restrict__ xsp, const uint16_t* __restrict__ wihp,
    const uint16_t* __restrict__ whhp, const float* __restrict__ bias,
    uint16_t* __restrict__ xp0, uint16_t* __restrict__ xp1,
    uint16_t* __restrict__ hst, float* __restrict__ cst,
    float* __restrict__ out, int lstm_chunk, int gemm_chunk) {
  extern __shared__ __align__(16) char lds[];
  const int tid = threadIdx.x;
  const int l = tid & 63;
  const int w = tid >> 6;

  if (blockIdx.x < 16) {
    // ======================= LSTM path =======================
    if (lstm_chunk < 0) return;
    const int c = lstm_chunk;
    const int blk = blockIdx.x;
    const uint16_t* __restrict__ xp = (c & 1) ? xp1 : xp0;
    char* wl = lds + w * WLDS_PER_WAVE;

    // ---- W residency: fi=(half*2+jt)*4+g; kt0,1 -> LDS, kt2-7 -> regs ----
    u32x4 wr[96];
#pragma unroll
    for (int fi = 0; fi < 16; ++fi) {
      int g = fi & 3, hj = fi >> 2;
      int nt = g * 16 + w * 4 + hj;
#pragma unroll
      for (int kt = 0; kt < 8; ++kt) {
        u32x4 d = *(const u32x4*)(whhp + (((size_t)nt * 8 + kt) * 64 + l) * 8);
        if (kt < 2)
          *(u32x4*)(wl + fi * 2048 + kt * 1024 + l * 16) = d;
        else
          wr[fi * 6 + (kt - 2)] = d;
      }
    }
    // c registers (16 cells/lane)
    float creg[16];
    {
      const float* cs = cst + ((size_t)(blk * 4 + w) * 64 + l) * 16;
#pragma unroll
      for (int v = 0; v < 16; ++v) creg[v] = cs[v];
    }
    // h(0) -> buffer 0
    {
      const char* src = (const char*)hst + (size_t)blk * 8192 + (size_t)tid * 32;
      *(u32x4*)(lds + HOFF + tid * 32) = *(const u32x4*)src;
      *(u32x4*)(lds + HOFF + tid * 32 + 16) = *(const u32x4*)(src + 16);
    }
    const char* xpb = (const char*)xp +
        ((((size_t)blk * 128) * 4 + w) * 2) * 4096 + (size_t)l * 64;
    float* ob = out + ((size_t)(blk * 16 + (l >> 4) * 4) * 1024 + (size_t)c * 128) * 256 + (l & 15);
    __syncthreads();

    union XV { uint16_t sv[32]; u32x4 v[4]; };

    int p = 0;
#pragma unroll 1
    for (int s = 0; s < 128; ++s) {
      const char* hb = lds + HOFF + p * 8192 + l * 16;
      char* hw = lds + HOFF + (p ^ 1) * 8192;
      const char* xc = xpb + (size_t)s * 32768;

      auto do_half = [&](int half, XV& xv) {
        f32x4 acc[2][4] = {};   // [jt][g]
#pragma unroll
        for (int kt = 0; kt < 8; ++kt) {
          u32x4 a = *(const u32x4*)(hb + kt * 1024);
#pragma unroll
          for (int jt = 0; jt < 2; ++jt)
#pragma unroll
            for (int g = 0; g < 4; ++g) {
              int fi = (half * 2 + jt) * 4 + g;
              u32x4 b = (kt < 2)
                  ? *(const u32x4*)(wl + fi * 2048 + kt * 1024 + l * 16)
                  : wr[fi * 6 + (kt - 2)];
              acc[jt][g] = mfma16(a, b, acc[jt][g]);
            }
        }
#pragma unroll
        for (int jt = 0; jt < 2; ++jt) {
          const int j = (w * 4 + half * 2 + jt) * 16 + (l & 15);
          char* hwj = hw + (j >> 5) * 1024 + ((j >> 3) & 3) * 256 +
                      (l >> 4) * 64 + (j & 7) * 2;
          float* obh = ob + (size_t)s * 256 + (w * 4 + half * 2 + jt) * 16;
#pragma unroll
          for (int q = 0; q < 4; ++q) {
            float xi = acc[jt][0][q] + bf2f(xv.sv[0 * 8 + jt * 4 + q]);
            float xf = acc[jt][1][q] + bf2f(xv.sv[1 * 8 + jt * 4 + q]);
            float xg = acc[jt][2][q] + bf2f(xv.sv[2 * 8 + jt * 4 + q]);
            float xo = acc[jt][3][q] + bf2f(xv.sv[3 * 8 + jt * 4 + q]);
            float I = frcp(1.f + exp2a(xi));
            float F = frcp(1.f + exp2a(xf));
            float T = fmaf(2.f, frcp(1.f + exp2a(xg)), -1.f);
            float O = frcp(1.f + exp2a(xo));
            int ci = half * 8 + jt * 4 + q;
            float cv = fmaf(F, creg[ci], I * T);
            creg[ci] = cv;
            float hv = O * fmaf(2.f, frcp(1.f + exp2a(SC_G * cv)), -1.f);
            obh[(size_t)q * 262144] = hv;
            *(uint16_t*)(hwj + q * 16) = f2bf(hv);
          }
        }
      };

      XV xv0;
      xv0.v[0] = *(const u32x4*)(xc);
      xv0.v[1] = *(const u32x4*)(xc + 16);
      xv0.v[2] = *(const u32x4*)(xc + 32);
      xv0.v[3] = *(const u32x4*)(xc + 48);
      do_half(0, xv0);
      XV xv1;
      xv1.v[0] = *(const u32x4*)(xc + 4096);
      xv1.v[1] = *(const u32x4*)(xc + 4096 + 16);
      xv1.v[2] = *(const u32x4*)(xc + 4096 + 32);
      xv1.v[3] = *(const u32x4*)(xc + 4096 + 48);
      do_half(1, xv1);
      __syncthreads();
      p ^= 1;
    }
    // write back carry state
    {
      const char* src = lds + HOFF + p * 8192 + tid * 32;
      char* dst = (char*)hst + (size_t)blk * 8192 + (size_t)tid * 32;
      *(u32x4*)dst = *(const u32x4*)src;
      *(u32x4*)(dst + 16) = *(const u32x4*)(src + 16);
      float* cs = cst + ((size_t)(blk * 4 + w) * 64 + l) * 16;
#pragma unroll
      for (int v = 0; v < 16; ++v) cs[v] = creg[v];
    }
    return;
  }

  // ======================= x_proj GEMM path =======================
  if (gemm_chunk < 0) return;
  const int cg = gemm_chunk;
  const int bid = blockIdx.x - 16;   // 0..255
  const int bb = bid & 15;           // batch group
  const int st = bid >> 4;           // s-group of 8
  uint16_t* __restrict__ xpo = (cg & 1) ? xp1 : xp0;

  float badd[4][4];                  // [g][jj]
#pragma unroll
  for (int g = 0; g < 4; ++g)
#pragma unroll
    for (int jj = 0; jj < 4; ++jj)
      badd[g][jj] = bias[(g * 16 + w * 4 + jj) * 16 + (l & 15)];

#pragma unroll 1
  for (int pr = 0; pr < 4; ++pr) {
    f32x4 acc[2][16] = {};           // [t][g*4+jj]
#pragma unroll
    for (int kt = 0; kt < 8; ++kt) {
      u32x4 av[2];
#pragma unroll
      for (int t = 0; t < 2; ++t) {
        size_t m16 = (size_t)(cg * 128 + st * 8 + pr * 2 + t) * 16 + bb;
        av[t] = *(const u32x4*)(xsp + ((m16 * 8 + kt) * 64 + l) * 8);
      }
      u32x4 bv[16];
#pragma unroll
      for (int fi = 0; fi < 16; ++fi) {
        int g = fi >> 2, jj = fi & 3;
        size_t nt = (size_t)(g * 16 + w * 4 + jj);
        bv[fi] = *(const u32x4*)(wihp + ((nt * 8 + kt) * 64 + l) * 8);
      }
#pragma unroll
      for (int t = 0; t < 2; ++t)
#pragma unroll
        for (int fi = 0; fi < 16; ++fi)
          acc[t][fi] = mfma16(av[t], bv[fi], acc[t][fi]);
    }
#pragma unroll
    for (int t = 0; t < 2; ++t) {
      int s = st * 8 + pr * 2 + t;
#pragma unroll
      for (int jj = 0; jj < 4; ++jj) {
        int half = jj >> 1, jt = jj & 1;
        char* dst = (char*)xpo +
            ((((size_t)bb * 128 + s) * 4 + w) * 2 + half) * 4096 +
            (size_t)l * 64 + jt * 8;
#pragma unroll
        for (int g = 0; g < 4; ++g) {
          union { uint16_t sv[4]; u32x2 v2; } pk;
#pragma unroll
          for (int q = 0; q < 4; ++q)
            pk.sv[q] = f2bf(acc[t][g * 4 + jj][q] + badd[g][jj]);
          *(u32x2*)(dst + g * 16) = pk.v2;
        }
      }
    }
  }
}

// ---------------------------------------------------------------------------
extern "C" void kernel_launch(void* const* d_in, const int* in_sizes, int n_in,
                              void* d_out, int out_size, void* d_ws, size_t ws_size,
                              hipStream_t stream) {
  const float* x   = (const float*)d_in[0];
  const float* hn  = (const float*)d_in[1];
  const float* cn  = (const float*)d_in[2];
  const float* wih = (const float*)d_in[3];
  const float* whh = (const float*)d_in[4];
  const float* bih = (const float*)d_in[5];
  const float* bhh = (const float*)d_in[6];
  float* out = (float*)d_out;
  char* ws = (char*)d_ws;

  uint16_t* xsp  = (uint16_t*)(ws + XS_OFF);
  uint16_t* wihp = (uint16_t*)(ws + WIH_OFF);
  uint16_t* whhp = (uint16_t*)(ws + WHH_OFF);
  uint16_t* xp0  = (uint16_t*)(ws + XP0_OFF);
  uint16_t* xp1  = (uint16_t*)(ws + XP1_OFF);
  uint16_t* hst  = (uint16_t*)(ws + HST_OFF);
  float*    cst  = (float*)(ws + CST_OFF);
  float*    bias = (float*)(ws + BIAS_OFF);

  hipFuncSetAttribute(reinterpret_cast<const void*>(fused_k),
                      hipFuncAttributeMaxDynamicSharedMemorySize, LDS_BYTES);

  hipLaunchKernelGGL(pack_x_k, dim3(2048), dim3(256), 0, stream, x, hn, xsp);
  hipLaunchKernelGGL(pack_misc_k, dim3(36), dim3(256), 0, stream,
                     wih, whh, bih, bhh, hn, cn, wihp, whhp, bias, hst, cst);
  for (int c = 0; c <= NCHUNK; ++c) {
    int lc = c - 1;
    int gc = (c < NCHUNK) ? c : -1;
    hipLaunchKernelGGL(fused_k, dim3(272), dim3(256), LDS_BYTES, stream,
                       xsp, wihp, whhp, bias, xp0, xp1, hst, cst, out, lc, gc);
  }
}